// Round 11
// baseline (223.450 us; speedup 1.0000x reference)
//
#include <hip/hip_runtime.h>
#include <hip/hip_bf16.h>

typedef short s16x8 __attribute__((ext_vector_type(8)));
typedef float f32x16 __attribute__((ext_vector_type(16)));

namespace {
constexpr int kB = 16;
constexpr int kD = 256;
constexpr int kHW = 16384;
constexpr int kM = 4096;
constexpr int kN = kB * kM;              // 65536 samples
constexpr int kWin = 1024;               // columns per window
constexpr int kKT = 16;                  // K-tile columns
constexpr int kNIter = kWin / kKT;       // 64 iterations
constexpr int kNBlk = 512;               // 16 b x 16 win x 2 col-halves
constexpr float kLam = 0.005f;

__device__ __forceinline__ unsigned short f2bf(float f) {
    union { float f; unsigned u; } x{f};
    const unsigned r = x.u + 0x7FFFu + ((x.u >> 16) & 1u);
    return (unsigned short)(r >> 16);
}
}

// barrier without vmcnt drain (prefetches stay in flight)
#define BAR_SOFT()                                            \
    do {                                                      \
        asm volatile("s_waitcnt lgkmcnt(0)" ::: "memory");    \
        __builtin_amdgcn_s_barrier();                         \
    } while (0)

// ---------------------------------------------------------------------------
// Kernel 1: per-b histogram of flat_idx -> counts c[b][p].
// ---------------------------------------------------------------------------
__global__ __launch_bounds__(256) void count_kernel(
    const int* __restrict__ flat_idx, int* __restrict__ cnt)
{
    __shared__ int h[kHW];
    const int t = threadIdx.x;
    const int b = blockIdx.x;
    for (int i = t; i < kHW; i += 256) h[i] = 0;
    __syncthreads();
    const int* bi = flat_idx + b * kM;
    for (int i = t; i < kM; i += 256) atomicAdd(&h[bi[i]], 1);
    __syncthreads();
    int* dst = cnt + b * kHW;
    for (int i = t; i < kHW; i += 256) dst[i] = h[i];
}

// ---------------------------------------------------------------------------
// Kernel 2: fused stream + weighted Gram + stats.
// Output tile 256x128 (col-half ch), acc 64 AGPR/wave -> <=128 total regs
// -> 2 independent blocks/CU (16 waves).  Inter-block overlap keeps the CU
// memory pipe busy while one block sits at its barrier (the R6-R10 variants
// were all 1 lock-step block/CU -> serial transfer+compute, ~6400cy/iter).
// ---------------------------------------------------------------------------
__global__ __launch_bounds__(512, 4) void fused_gram_kernel(
    const float* __restrict__ z, const float* __restrict__ zp,
    const int* __restrict__ cnt,
    float* __restrict__ partial, float* __restrict__ statsPart)
{
    __shared__ char smem[24576];   // buf: A 8KB + B 4KB; two bufs

    const int bx = blockIdx.x;
    const int b = bx & (kB - 1);
    const int win0 = ((bx >> 4) & 15) * kWin;
    const int ch = bx >> 8;                   // 0/1: Gram cols 0-127 / 128-255
    const int t = threadIdx.x;
    const int w = t >> 6, lane = t & 63, l31 = lane & 31, half = lane >> 5;
    const int wr = w >> 1;          // 0..3  row block of 64
    const int wc = w & 1;           // 0..1  col block of 64
    const int row2 = t >> 2;        // 0..127 staging row
    const int cg = t & 3;           // 0..3   staging col group (4 f32)

    const float* zb  = z  + (size_t)b * kD * kHW;
    const float* zpb = zp + ((size_t)b * kD + 128 * ch) * kHW;
    const int* cb = cnt + b * kHW;

    f32x16 acc[2][2];
#pragma unroll
    for (int i = 0; i < 2; ++i)
#pragma unroll
        for (int j = 0; j < 2; ++j)
#pragma unroll
            for (int r = 0; r < 16; ++r) acc[i][j][r] = 0.f;

    float sA[2], ssA[2], sB, ssB;
    sA[0] = sA[1] = ssA[0] = ssA[1] = sB = ssB = 0.f;

    // single staging register set
    float4 vA0, vA1, vB;
    int4 ci;

    auto LOAD = [&](int kt) {
        const int base = win0 + kt * kKT + cg * 4;
        vA0 = *(const float4*)(zb + (size_t)row2 * kHW + base);
        vA1 = *(const float4*)(zb + (size_t)(row2 + 128) * kHW + base);
        vB  = *(const float4*)(zpb + (size_t)row2 * kHW + base);
        ci  = *(const int4*)(cb + base);
    };

    auto CONV = [&](int buf) {
        char* As = smem + buf * 12288;
        char* Bs = As + 8192;
        const float cf[4] = {(float)ci.x, (float)ci.y, (float)ci.z, (float)ci.w};
        const float4 va[2] = {vA0, vA1};
#pragma unroll
        for (int q = 0; q < 2; ++q) {
            const int row = row2 + 128 * q;
            const float a[4] = {va[q].x, va[q].y, va[q].z, va[q].w};
            ushort4 pa;
            unsigned short* pav = (unsigned short*)&pa;
#pragma unroll
            for (int j = 0; j < 4; ++j) {
                if (ch == 0) {
                    sA[q] = fmaf(cf[j], a[j], sA[q]);
                    ssA[q] = fmaf(cf[j], a[j] * a[j], ssA[q]);
                }
                pav[j] = f2bf(a[j]);
            }
            const int off = (((cg >> 1) * 256 + row) << 4) + ((cg & 1) << 3);
            *(unsigned long long*)(As + off) = *(unsigned long long*)&pa;
        }
        {
            const float bb[4] = {vB.x, vB.y, vB.z, vB.w};
            ushort4 pb;
            unsigned short* pbv = (unsigned short*)&pb;
#pragma unroll
            for (int j = 0; j < 4; ++j) {
                const float wb = cf[j] * bb[j];
                sB = fmaf(cf[j], bb[j], sB);
                ssB = fmaf(cf[j], bb[j] * bb[j], ssB);
                pbv[j] = f2bf(wb);
            }
            const int off = (((cg >> 1) * 128 + row2) << 4) + ((cg & 1) << 3);
            *(unsigned long long*)(Bs + off) = *(unsigned long long*)&pb;
        }
    };

    auto MFMA_STEP = [&](int buf) {
        const char* As = smem + buf * 12288;
        const char* Bs = As + 8192;
        s16x8 af[2], bfr[2];
#pragma unroll
        for (int rt = 0; rt < 2; ++rt) {
            const int row = 64 * wr + 32 * rt + l31;
            af[rt] = *(const s16x8*)(As + ((half * 256 + row) << 4));
        }
#pragma unroll
        for (int ct = 0; ct < 2; ++ct) {
            const int row = 64 * wc + 32 * ct + l31;
            bfr[ct] = *(const s16x8*)(Bs + ((half * 128 + row) << 4));
        }
#pragma unroll
        for (int rt = 0; rt < 2; ++rt)
#pragma unroll
            for (int ct = 0; ct < 2; ++ct)
                acc[rt][ct] = __builtin_amdgcn_mfma_f32_32x32x16_bf16(
                    af[rt], bfr[ct], acc[rt][ct], 0, 0, 0);
    };

    // Prologue: tile0 -> buf0; preload tile1.
    LOAD(0);
    CONV(0);
    LOAD(1);
    BAR_SOFT();

    for (int kt = 0; kt < kNIter; ++kt) {
        if (kt + 1 < kNIter) CONV((kt + 1) & 1);   // consumes reg set (tile kt+1)
        if (kt + 2 < kNIter) LOAD(kt + 2);         // refill, issue early
        MFMA_STEP(kt & 1);                         // tile kt
        BAR_SOFT();
    }
    __syncthreads();   // full drain before smem reuse

    // 256x128 partial Gram
    float* out = partial + (size_t)bx * (kD * 128);
#pragma unroll
    for (int rt = 0; rt < 2; ++rt)
#pragma unroll
        for (int ct = 0; ct < 2; ++ct)
#pragma unroll
            for (int r = 0; r < 16; ++r) {
                const int row = 64 * wr + 32 * rt + (r & 3) + 8 * (r >> 2) + 4 * half;
                const int col = 64 * wc + 32 * ct + l31;
                out[row * 128 + col] = acc[rt][ct][r];
            }

    // stats reduce via (dead) LDS: sdA [256][4][2] = 8KB, sdB [128][4][2] = 4KB
    float* sdA = (float*)smem;
    float* sdB = (float*)(smem + 8192);
    if (ch == 0) {
#pragma unroll
        for (int q = 0; q < 2; ++q) {
            const int row = row2 + 128 * q;
            sdA[(row * 4 + cg) * 2 + 0] = sA[q];
            sdA[(row * 4 + cg) * 2 + 1] = ssA[q];
        }
    }
    sdB[(row2 * 4 + cg) * 2 + 0] = sB;
    sdB[(row2 * 4 + cg) * 2 + 1] = ssB;
    __syncthreads();
    if (t < kD) {
        const int r = t;
        float as_ = 0.f, ass_ = 0.f, bs_ = 0.f, bss_ = 0.f;
        if (ch == 0) {
#pragma unroll
            for (int g = 0; g < 4; ++g) {
                as_ += sdA[(r * 4 + g) * 2];
                ass_ += sdA[(r * 4 + g) * 2 + 1];
            }
        }
        if ((r >> 7) == ch) {
            const int lb = r & 127;
#pragma unroll
            for (int g = 0; g < 4; ++g) {
                bs_ += sdB[(lb * 4 + g) * 2];
                bss_ += sdB[(lb * 4 + g) * 2 + 1];
            }
        }
        float4 v = {as_, ass_, bs_, bss_};
        *(float4*)(statsPart + ((size_t)bx * kD + r) * 4) = v;
    }
}

// ---------------------------------------------------------------------------
// Kernel 3: reduce partial Grams (512 x [256][128]) -> G; stats -> statsRed.
// ---------------------------------------------------------------------------
__global__ __launch_bounds__(256) void reduce_gram_kernel(
    const float* __restrict__ partial, const float* __restrict__ statsPart,
    float* __restrict__ G, float* __restrict__ statsRed)
{
    const int d = blockIdx.x;
    const int e = threadIdx.x;
    const int chh = e >> 7, el = e & 127;
    float s = 0.f;
#pragma unroll 8
    for (int i = 0; i < 256; ++i)
        s += partial[(size_t)(chh * 256 + i) * (kD * 128) + d * 128 + el];
    G[d * kD + e] = s;

    // stats: thread e sums slabs e and e+256, row d
    const float4 v1 = *(const float4*)(statsPart + ((size_t)e * kD + d) * 4);
    const float4 v2 = *(const float4*)(statsPart + ((size_t)(e + 256) * kD + d) * 4);
    float x0 = v1.x + v2.x, x1 = v1.y + v2.y, x2 = v1.z + v2.z, x3 = v1.w + v2.w;
#pragma unroll
    for (int o = 32; o; o >>= 1) {
        x0 += __shfl_down(x0, o);
        x1 += __shfl_down(x1, o);
        x2 += __shfl_down(x2, o);
        x3 += __shfl_down(x3, o);
    }
    __shared__ float r[4][4];
    if ((e & 63) == 0) {
        r[e >> 6][0] = x0; r[e >> 6][1] = x1;
        r[e >> 6][2] = x2; r[e >> 6][3] = x3;
    }
    __syncthreads();
    if (e < 4) {
        statsRed[d * 4 + e] = r[0][e] + r[1][e] + r[2][e] + r[3][e];
    }
}

// ---------------------------------------------------------------------------
// Kernel 4: final loss (single block).
// ---------------------------------------------------------------------------
__global__ __launch_bounds__(256) void loss_kernel(
    const float* __restrict__ G, const float* __restrict__ statsRed,
    float* __restrict__ out)
{
    __shared__ float muA[kD], isA[kD], muB[kD], isB[kD];
    const int t = threadIdx.x;
    const float4 v = *(const float4*)(statsRed + t * 4);
    const float n = (float)kN;
    const float mA = v.x / n, mB = v.z / n;
    const float vA = (v.y - n * mA * mA) / (n - 1.f);
    const float vB = (v.w - n * mB * mB) / (n - 1.f);
    const float sdA = fmaxf(sqrtf(fmaxf(vA, 0.f)), 1e-6f);
    const float sdB = fmaxf(sqrtf(fmaxf(vB, 0.f)), 1e-6f);
    muA[t] = mA; isA[t] = 1.f / sdA;
    muB[t] = mB; isB[t] = 1.f / sdB;
    __syncthreads();

    float acc = 0.f;
    for (int d = 0; d < kD; ++d) {
        const int e = t;
        const float c = (G[d * kD + e] / n - muA[d] * muB[e]) * isA[d] * isB[e];
        if (d == e) { const float u = 1.f - c; acc += u * u; }
        else        { acc += kLam * c * c; }
    }
#pragma unroll
    for (int o = 32; o; o >>= 1) acc += __shfl_down(acc, o);
    __shared__ float r[4];
    if ((t & 63) == 0) r[t >> 6] = acc;
    __syncthreads();
    if (t == 0) out[0] = r[0] + r[1] + r[2] + r[3];
}

// ---------------------------------------------------------------------------
extern "C" void kernel_launch(void* const* d_in, const int* in_sizes, int n_in,
                              void* d_out, int out_size, void* d_ws, size_t ws_size,
                              hipStream_t stream) {
    const float* z  = (const float*)d_in[0];
    const float* zp = (const float*)d_in[1];
    const int* flat_idx = (const int*)d_in[2];
    float* out = (float*)d_out;

    char* ws = (char*)d_ws;
    // ws layout:
    //   [0, 1MB)        counts  int [16][16384]
    //   [1MB, 3MB)      statsPart f32 [512][256][4]
    //   [3MB, +4K)      statsRed f32 [256][4]
    //   [3MB+64K,+256K) G f32 [256][256]
    //   [16MB, 32MB)    partial f32 [512][256][128]
    int* cnt = (int*)ws;
    float* statsPart = (float*)(ws + (size_t)1 * 1024 * 1024);
    float* statsRed  = (float*)(ws + (size_t)3 * 1024 * 1024);
    float* G = (float*)(ws + (size_t)3 * 1024 * 1024 + 64 * 1024);
    float* partial = (float*)(ws + (size_t)16 * 1024 * 1024);

    count_kernel<<<kB, 256, 0, stream>>>(flat_idx, cnt);
    fused_gram_kernel<<<kNBlk, 512, 0, stream>>>(z, zp, cnt, partial, statsPart);
    reduce_gram_kernel<<<kD, 256, 0, stream>>>(partial, statsPart, G, statsRed);
    loss_kernel<<<1, 256, 0, stream>>>(G, statsRed, out);
}